// Round 2
// baseline (911.183 us; speedup 1.0000x reference)
//
#include <hip/hip_runtime.h>
#include <hip/hip_bf16.h>
#include <stdint.h>

typedef __bf16 bf16_t;
typedef __bf16 bf16x4 __attribute__((ext_vector_type(4)));
typedef __bf16 bf16x8 __attribute__((ext_vector_type(8)));
typedef float  f32x4  __attribute__((ext_vector_type(4)));

#define AS_G __attribute__((address_space(1)))
#define AS_L __attribute__((address_space(3)))

// ---------------- weight cast: all 4 weights in one launch ----------------
struct CastArgs { const float* s0; const float* s1; const float* s2; const float* s3; bf16_t* dst; };

__global__ void cast_weights(CastArgs c) {
    const int w = blockIdx.x >> 10;                       // 1024 blocks per 1M-elem weight
    const float* src = (w == 0) ? c.s0 : (w == 1) ? c.s1 : (w == 2) ? c.s2 : c.s3;
    const int i = (blockIdx.x & 1023) * 256 + threadIdx.x;
    float4 v = ((const float4*)src)[i];
    bf16x4 o;
    o.x = (bf16_t)v.x; o.y = (bf16_t)v.y; o.z = (bf16_t)v.z; o.w = (bf16_t)v.w;
    ((bf16x4*)(c.dst + ((size_t)w << 20)))[i] = o;
}

// ---------------- GEMM core: C[M,N] = A[M,K] * Bt[N,K]^T + bias ----------------
// 128x128 tile, BK=32, 4 waves, 4x4 16x16x32 MFMA per wave.
// LDS XOR swizzle: source chunk c of row r stored at position c ^ f(r); the
// global source address is lane-permuted so the LDS dest stays base + lane*16
// (global_load_lds constraint). Spreads frag-read banks -> <=2-way (free).
//   bf16 rows (32 elem = 4x16B chunks): f(r) = (r>>1)&3
//   f32  rows (32 elem = 8x16B chunks): f(r) = r&7
template<int A_F32, int OUT_BF16>
__device__ __forceinline__ void gemm_core(const void* __restrict__ Av,
                                          const bf16_t* __restrict__ Bt,
                                          const float* __restrict__ bias,
                                          void* __restrict__ Cout,
                                          int M, int N, int K, int m0, int n0,
                                          void* AsRaw, bf16_t* __restrict__ Bs) {
    const int tid  = threadIdx.x;
    const int wave = tid >> 6, lane = tid & 63;
    const int quad = lane >> 4, r16 = lane & 15;
    const int wm = (wave >> 1) * 64, wn = (wave & 1) * 64;

    // B (bf16) staging: rows wave*32 + t*16 + (lane>>2), src chunk (lane&3)^((lane>>3)&3)
    const int brow = lane >> 2;
    const int cb   = (lane & 3) ^ ((lane >> 3) & 3);
    const bf16_t* gb = Bt + (size_t)(n0 + (wave << 5) + brow) * K + cb * 8;
    bf16_t* lb = Bs + ((wave << 5) + brow) * 32 + (lane & 3) * 8;

    const int fb = (r16 >> 1) & 3;
    int boff[4];
#pragma unroll
    for (int t = 0; t < 4; ++t)
        boff[t] = (wn + t * 16 + r16) * 32 + ((quad ^ fb) << 3);

    f32x4 acc[4][4] = {};

    if (A_F32) {
        const float* A = (const float*)Av;
        float* Asf = (float*)AsRaw;
        const int arow = lane >> 3;                    // 0..7
        const int ca   = (lane & 7) ^ arow;            // src chunk 0..7
        const float* ga = A + (size_t)(m0 + (wave << 5) + arow) * K + ca * 4;
        float* la = Asf + ((wave << 5) + arow) * 32 + (lane & 7) * 4;

        const int fa = r16 & 7;
        int aoff0[4], aoff1[4];
#pragma unroll
        for (int t = 0; t < 4; ++t) {
            const int rowA = (wm + t * 16 + r16) * 32;
            aoff0[t] = rowA + (((2 * quad    ) ^ fa) << 2);
            aoff1[t] = rowA + (((2 * quad + 1) ^ fa) << 2);
        }

        for (int k0 = 0; k0 < K; k0 += 32) {
#pragma unroll
            for (int t = 0; t < 4; ++t)
                __builtin_amdgcn_global_load_lds((const AS_G void*)(ga + (size_t)t * 8 * K + k0),
                                                 (AS_L void*)(la + t * 256), 16, 0, 0);
#pragma unroll
            for (int t = 0; t < 2; ++t)
                __builtin_amdgcn_global_load_lds((const AS_G void*)(gb + (size_t)t * 16 * K + k0),
                                                 (AS_L void*)(lb + t * 512), 16, 0, 0);
            __syncthreads();

            bf16x8 aF[4], bF[4];
#pragma unroll
            for (int t = 0; t < 4; ++t) {
                f32x4 a0 = *(const f32x4*)&Asf[aoff0[t]];
                f32x4 a1 = *(const f32x4*)&Asf[aoff1[t]];
                bf16x8 af;
#pragma unroll
                for (int j = 0; j < 4; ++j) { af[j] = (bf16_t)a0[j]; af[4 + j] = (bf16_t)a1[j]; }
                aF[t] = af;
                bF[t] = *(const bf16x8*)&Bs[boff[t]];
            }
#pragma unroll
            for (int tm = 0; tm < 4; ++tm)
#pragma unroll
                for (int tn = 0; tn < 4; ++tn)
                    acc[tm][tn] = __builtin_amdgcn_mfma_f32_16x16x32_bf16(aF[tm], bF[tn], acc[tm][tn], 0, 0, 0);
            __syncthreads();
        }
    } else {
        const bf16_t* A = (const bf16_t*)Av;
        bf16_t* As = (bf16_t*)AsRaw;
        const int arow = lane >> 2;
        const int caA  = (lane & 3) ^ ((lane >> 3) & 3);
        const bf16_t* ga = A + (size_t)(m0 + (wave << 5) + arow) * K + caA * 8;
        bf16_t* la = As + ((wave << 5) + arow) * 32 + (lane & 3) * 8;

        int aoff[4];
#pragma unroll
        for (int t = 0; t < 4; ++t)
            aoff[t] = (wm + t * 16 + r16) * 32 + ((quad ^ fb) << 3);

        for (int k0 = 0; k0 < K; k0 += 32) {
#pragma unroll
            for (int t = 0; t < 2; ++t) {
                __builtin_amdgcn_global_load_lds((const AS_G void*)(ga + (size_t)t * 16 * K + k0),
                                                 (AS_L void*)(la + t * 512), 16, 0, 0);
                __builtin_amdgcn_global_load_lds((const AS_G void*)(gb + (size_t)t * 16 * K + k0),
                                                 (AS_L void*)(lb + t * 512), 16, 0, 0);
            }
            __syncthreads();

            bf16x8 aF[4], bF[4];
#pragma unroll
            for (int t = 0; t < 4; ++t) {
                aF[t] = *(const bf16x8*)&As[aoff[t]];
                bF[t] = *(const bf16x8*)&Bs[boff[t]];
            }
#pragma unroll
            for (int tm = 0; tm < 4; ++tm)
#pragma unroll
                for (int tn = 0; tn < 4; ++tn)
                    acc[tm][tn] = __builtin_amdgcn_mfma_f32_16x16x32_bf16(aF[tm], bF[tn], acc[tm][tn], 0, 0, 0);
            __syncthreads();
        }
    }

    float bv[4];
#pragma unroll
    for (int tn = 0; tn < 4; ++tn) bv[tn] = bias[n0 + wn + tn * 16 + r16];

#pragma unroll
    for (int tm = 0; tm < 4; ++tm) {
#pragma unroll
        for (int r = 0; r < 4; ++r) {
            const int m = m0 + wm + tm * 16 + quad * 4 + r;
#pragma unroll
            for (int tn = 0; tn < 4; ++tn) {
                const int n = n0 + wn + tn * 16 + r16;
                const float v = acc[tm][tn][r] + bv[tn];
                if (OUT_BF16) ((bf16_t*)Cout)[(size_t)m * N + n] = (bf16_t)v;
                else          ((float*)Cout)[(size_t)m * N + n]  = v;
            }
        }
    }
}

// ---- QKV batched GEMM: fp32 A (cast fused into staging), blockIdx.z in {0,1,2} ----
struct QkvArgs {
    const float* A0; const float* A1; const float* A2;
    const bf16_t* Bt;                         // Wq,Wk,Wv contiguous, stride K*N
    const float* b0; const float* b1; const float* b2;
    bf16_t* C;                                // Qb,Kb,Vb contiguous, stride M*N
};

__global__ __launch_bounds__(256) void gemm_qkv(QkvArgs q, int M, int N, int K) {
    __shared__ float  Asf[128 * 32];
    __shared__ bf16_t Bs[128 * 32];
    const int z = blockIdx.z;
    const float* A    = (z == 0) ? q.A0 : (z == 1) ? q.A1 : q.A2;
    const float* bias = (z == 0) ? q.b0 : (z == 1) ? q.b1 : q.b2;
    gemm_core<1, 1>(A, q.Bt + (size_t)z * N * K, bias, q.C + (size_t)z * M * N,
                    M, N, K, blockIdx.y * 128, blockIdx.x * 128, Asf, Bs);
}

// ---- output GEMM: bf16 A (M2), fp32 out ----
__global__ __launch_bounds__(256) void gemm_out(const bf16_t* __restrict__ A,
                                                const bf16_t* __restrict__ Bt,
                                                const float* __restrict__ bias,
                                                float* __restrict__ C,
                                                int M, int N, int K) {
    __shared__ bf16_t As[128 * 32];
    __shared__ bf16_t Bs[128 * 32];
    gemm_core<0, 0>(A, Bt, bias, C, M, N, K, blockIdx.y * 128, blockIdx.x * 128, As, Bs);
}

// ---------------- attention: one wave per (b,a) position ----------------
// scores (16x16 across heads) = QK^T/(sqrt(64)*alpha); sparsemax per row via
// per-lane bitonic network; PV with V^T staged in swizzled LDS (vector global
// loads, <=2-way-bank LDS reads); output repacked through LDS so the scrambled
// M2 write (torch transpose(1,2).view) is 2x16B per lane.
__global__ void attn_kernel(const bf16_t* __restrict__ Q, const bf16_t* __restrict__ K,
                            const bf16_t* __restrict__ V, bf16_t* __restrict__ M2) {
    __shared__ bf16_t vt[4][2048];         // V^T (64 rows x 32 pitch, swizzled); reused for out repack
    __shared__ float  zs_s[4][16][17];
    __shared__ float  tau_s[4][16];
    const int wave = threadIdx.x >> 6, lane = threadIdx.x & 63;
    const int quad = lane >> 4, g16 = lane & 15;
    const int p = blockIdx.x * 4 + wave;   // p = a*8 + b
    const int a = p >> 3, b = p & 7;
    const bf16_t* q = Q + (size_t)p * 1024;
    const bf16_t* k = K + (size_t)p * 1024;
    const bf16_t* v = V + (size_t)p * 1024;

    bf16x8 qa0 = *(const bf16x8*)(q + g16 * 64 + quad * 8);
    bf16x8 qa1 = *(const bf16x8*)(q + g16 * 64 + 32 + quad * 8);
    bf16x8 ka0 = *(const bf16x8*)(k + g16 * 64 + quad * 8);
    bf16x8 ka1 = *(const bf16x8*)(k + g16 * 64 + 32 + quad * 8);
    bf16x8 v0  = *(const bf16x8*)(v + lane * 16);
    bf16x8 v1  = *(const bf16x8*)(v + lane * 16 + 8);

    // V^T scatter: lane holds V[g = lane>>2][e = (lane&3)*16 + j], j=0..15.
    // store at e*32 + ((g>>3) ^ ((e>>1)&3))*8 + (g&7)
    {
        bf16_t* vtw = vt[wave];
        const int g = lane >> 2, gh = g >> 3, gl = g & 7;
        const int eb = (lane & 3) * 16;
#pragma unroll
        for (int j = 0; j < 16; ++j) {
            const int e = eb + j;
            vtw[e * 32 + ((gh ^ ((e >> 1) & 3)) << 3) + gl] = (j < 8) ? v0[j] : v1[j - 8];
        }
    }

    f32x4 sc = {0.f, 0.f, 0.f, 0.f};
    sc = __builtin_amdgcn_mfma_f32_16x16x32_bf16(qa0, ka0, sc, 0, 0, 0);
    sc = __builtin_amdgcn_mfma_f32_16x16x32_bf16(qa1, ka1, sc, 0, 0, 0);

    const float inv = 1.0f / 12.0f;        // 1/(sqrt(64)*1.5)
#pragma unroll
    for (int r = 0; r < 4; ++r) zs_s[wave][quad * 4 + r][g16] = sc[r] * inv;
    __syncthreads();

    if (lane < 16) {                        // row h = lane: sparsemax over 16 vals
        float z[16];
#pragma unroll
        for (int j = 0; j < 16; ++j) z[j] = zs_s[wave][lane][j];
#pragma unroll
        for (int kk = 2; kk <= 16; kk <<= 1) {
#pragma unroll
            for (int j = kk >> 1; j > 0; j >>= 1) {
#pragma unroll
                for (int i = 0; i < 16; ++i) {
                    int ixj = i ^ j;
                    if (ixj > i) {
                        bool desc = ((i & kk) == 0);
                        float zi = z[i], zj = z[ixj];
                        bool sw = desc ? (zi < zj) : (zi > zj);
                        z[i]   = sw ? zj : zi;
                        z[ixj] = sw ? zi : zj;
                    }
                }
            }
        }
        float cum = 0.f, csel = 0.f;
        int ksel = 1;
#pragma unroll
        for (int j = 0; j < 16; ++j) {
            cum += z[j];
            bool sup = z[j] * (float)(j + 1) > (cum - 1.0f);
            ksel = sup ? (j + 1) : ksel;
            csel = sup ? cum : csel;
        }
        tau_s[wave][lane] = (csel - 1.0f) / (float)ksel;
    }
    __syncthreads();

#pragma unroll
    for (int r = 0; r < 4; ++r) {
        float av = sc[r] * inv - tau_s[wave][quad * 4 + r];
        zs_s[wave][quad * 4 + r][g16] = av > 0.f ? av : 0.f;
    }
    __syncthreads();

    // PV: A-frag attn[h=lane&15][g=quad*8+j] (quads 2,3 -> zero pad);
    // B-frag V^T[e][g] from swizzled LDS.
    bf16x8 aP;
#pragma unroll
    for (int j = 0; j < 8; ++j)
        aP[j] = (quad < 2) ? (bf16_t)zs_s[wave][g16][quad * 8 + j] : (bf16_t)0.f;

    const bf16_t* vtw = vt[wave];
    const int fv = (g16 >> 1) & 3;
    f32x4 oc[4];
#pragma unroll
    for (int c = 0; c < 4; ++c) {
        bf16x8 bV;
        if (quad < 2) {
            bV = *(const bf16x8*)&vtw[(c * 16 + g16) * 32 + ((quad ^ fv) << 3)];
        } else {
#pragma unroll
            for (int j = 0; j < 8; ++j) bV[j] = (bf16_t)0.f;
        }
        f32x4 z4 = {0.f, 0.f, 0.f, 0.f};
        oc[c] = __builtin_amdgcn_mfma_f32_16x16x32_bf16(aP, bV, z4, 0, 0, 0);
    }
    __syncthreads();                        // vt reads done before overwrite

    // repack out[h][e] (16x64, pitch 72) then 2x16B coalesced M2 stores
    {
        bf16_t* ob = vt[wave];
#pragma unroll
        for (int c = 0; c < 4; ++c)
#pragma unroll
            for (int r = 0; r < 4; ++r)
                ob[(quad * 4 + r) * 72 + c * 16 + g16] = (bf16_t)oc[c][r];
    }
    __syncthreads();
    {
        const bf16_t* ob = vt[wave];
        const int hh = lane >> 2, e0 = (lane & 3) * 16;
        bf16x8 o0 = *(const bf16x8*)&ob[hh * 72 + e0];
        bf16x8 o1 = *(const bf16x8*)&ob[hh * 72 + e0 + 8];
        const size_t m2row = (size_t)(hh * 256 + (a >> 4)) * 8 + b;
        bf16_t* dst = M2 + m2row * 1024 + ((a & 15) << 6) + e0;
        *(bf16x8*)dst = o0;
        *(bf16x8*)(dst + 8) = o1;
    }
}

// ---------------- launch ----------------
extern "C" void kernel_launch(void* const* d_in, const int* in_sizes, int n_in,
                              void* d_out, int out_size, void* d_ws, size_t ws_size,
                              hipStream_t stream) {
    (void)in_sizes; (void)n_in; (void)out_size; (void)ws_size;
    const float* query = (const float*)d_in[0];
    const float* key   = (const float*)d_in[1];
    const float* value = (const float*)d_in[2];
    const float* Wq = (const float*)d_in[3];
    const float* bq = (const float*)d_in[4];
    const float* Wk = (const float*)d_in[5];
    const float* bk = (const float*)d_in[6];
    const float* Wv = (const float*)d_in[7];
    const float* bv = (const float*)d_in[8];
    const float* Wo = (const float*)d_in[9];
    const float* bo = (const float*)d_in[10];

    const int M = 32768, D = 1024;
    const size_t MD = (size_t)M * D;

    bf16_t* Qb = (bf16_t*)d_ws;            // Q,K,V,M2 contiguous
    bf16_t* Kb = Qb + MD;
    bf16_t* Vb = Kb + MD;
    bf16_t* M2 = Vb + MD;
    bf16_t* Wb = M2 + MD;                  // Wq,Wk,Wv,Wo bf16, contiguous

    CastArgs ca = {Wq, Wk, Wv, Wo, Wb};
    cast_weights<<<4096, 256, 0, stream>>>(ca);

    QkvArgs qa = {query, key, value, Wb, bq, bk, bv, Qb};
    gemm_qkv<<<dim3(D / 128, M / 128, 3), 256, 0, stream>>>(qa, M, D, D);

    attn_kernel<<<M / 4, 256, 0, stream>>>(Qb, Kb, Vb, M2);

    gemm_out<<<dim3(D / 128, M / 128), 256, 0, stream>>>(M2, Wb + 3 * (size_t)D * D, bo,
                                                         (float*)d_out, M, D, D);
}